// Round 6
// baseline (660.642 us; speedup 1.0000x reference)
//
#include <hip/hip_runtime.h>
#include <hip/hip_bf16.h>

#define B_ 2
#define N_ 384
#define D_ 128
#define LAT_ 256
#define NPOS_ 33
#define ROWS_ (B_*N_)   // 768

typedef __attribute__((ext_vector_type(8))) short bf16x8;
typedef __attribute__((ext_vector_type(4))) float f32x4;

#define MFMA(a,b,c) __builtin_amdgcn_mfma_f32_16x16x32_bf16((a),(b),(c),0,0,0)

__device__ __forceinline__ unsigned short f2bf(float x) {
    unsigned int u = __float_as_uint(x);
    u += 0x7FFFu + ((u >> 16) & 1u);   // round-to-nearest-even
    return (unsigned short)(u >> 16);
}

__device__ __forceinline__ float bn_apply(float x, const float* stats, const float* gam,
                                          const float* bet, int d) {
    float s  = stats[d], sq = stats[128 + d];
    float mean = s * (1.f/ROWS_);
    float var  = sq * (1.f/ROWS_) - mean*mean;
    return (x - mean) * rsqrtf(var + 1e-5f) * gam[d] + bet[d];
}

// ---------------- encode ----------------
__global__ __launch_bounds__(256) void enc_kernel(const float* __restrict__ feats,
                           const float* __restrict__ W,
                           const float* __restrict__ bias,
                           float* __restrict__ f) {
    int i = blockIdx.x*256 + threadIdx.x;
    if (i >= ROWS_*D_) return;
    int r = i >> 7, d = i & 127;
    f[i] = feats[r]*W[d] + bias[d];
}

// ---------------- qkv (+ fused bn-apply on input) ----------------
__global__ __launch_bounds__(128) void qkv_kernel(const float* __restrict__ graw,
    const float* __restrict__ stats, const float* __restrict__ gam, const float* __restrict__ bet,
    int use_stats,
    const float* __restrict__ Wq, const float* __restrict__ Wk, const float* __restrict__ Wv,
    float* __restrict__ q, float* __restrict__ k, float* __restrict__ v) {
    __shared__ float row[D_];
    int r = blockIdx.x, d = threadIdx.x;
    float x = graw[r*D_+d];
    if (use_stats) x = bn_apply(x, stats, gam, bet, d);
    row[d] = x;
    __syncthreads();
    float aq=0.f, ak=0.f, av=0.f;
    #pragma unroll 4
    for (int e4=0;e4<D_/4;e4++){
        float4 wq = *(const float4*)(Wq + d*D_ + e4*4);
        float4 wk = *(const float4*)(Wk + d*D_ + e4*4);
        float4 wv = *(const float4*)(Wv + d*D_ + e4*4);
        float x0=row[e4*4+0], x1=row[e4*4+1], x2=row[e4*4+2], x3=row[e4*4+3];
        aq += wq.x*x0 + wq.y*x1 + wq.z*x2 + wq.w*x3;
        ak += wk.x*x0 + wk.y*x1 + wk.z*x2 + wk.w*x3;
        av += wv.x*x0 + wv.y*x1 + wv.z*x2 + wv.w*x3;
    }
    q[r*D_+d]=aq; k[r*D_+d]=ak; v[r*D_+d]=av;
}

// ---------------- MFMA attention, 3-barrier schedule, K/V direct from global ----------------
// 512 thr = 8 waves: rb = w>>2 (n-rowblock of 16), ct0 = (w&3)*2 (two d-tiles of 16).
// Loop slots: S1 Wg1(sX->sH) | bar | S2 Wg2(sH)+exp/accum(v global)+partsgen(i+1) | bar |
//             S3 posGEMM(sParts)+edges(k global)->sX | bar.  Single-buffered (WAR >= 1 bar).
__global__ __launch_bounds__(512) void attn_mfma_kernel(
    const float* __restrict__ xyz, const float* __restrict__ graw,
    const float* __restrict__ stats_in, const float* __restrict__ gam_in,
    const float* __restrict__ bet_in, int use_stats,
    const float* __restrict__ qb, const float* __restrict__ kb, const float* __restrict__ vb,
    const float* __restrict__ Wpe, const float* __restrict__ bpe,
    const float* __restrict__ Wg1, const float* __restrict__ bg1,
    const float* __restrict__ Wg2, const float* __restrict__ bg2,
    float* __restrict__ gout, float* __restrict__ stats_out)
{
    __shared__ unsigned short sParts[32*64];   // bf16, swizzled, K-padded zeros
    __shared__ unsigned short sX[32*128];      // edges bf16, swizzled
    __shared__ unsigned short sH[32*128];      // h bf16, swizzled
    __shared__ float sRed[4*128];

    const int t   = threadIdx.x;
    const int w   = t >> 6;
    const int l   = t & 63;
    const int lr  = l & 15;
    const int lg  = l >> 4;
    const int rb  = w >> 2;
    const int ct0 = (w & 3) * 2;

    const int row  = blockIdx.x;
    const int b    = row / N_;
    const int brow = b * N_;

    // ---- prologue: register B-fragments (bf16) + per-col scalars ----
    bf16x8 bWg1[2][4], bWg2[2][4], bWpe[2][2];
    float  bpe_c[2], bg1_c[2], bg2_c[2], q_c[2];

    #pragma unroll
    for (int ct = 0; ct < 2; ++ct) {
        const int dout = (ct0 + ct) * 16 + lr;
        #pragma unroll
        for (int kt = 0; kt < 4; ++kt) {
            const float* p1 = Wg1 + dout * D_ + kt * 32 + lg * 8;
            const float* p2 = Wg2 + dout * D_ + kt * 32 + lg * 8;
            float4 a0 = *(const float4*)(p1);
            float4 a1 = *(const float4*)(p1 + 4);
            float4 c0 = *(const float4*)(p2);
            float4 c1 = *(const float4*)(p2 + 4);
            bf16x8 v1, v2;
            v1[0]=(short)f2bf(a0.x); v1[1]=(short)f2bf(a0.y); v1[2]=(short)f2bf(a0.z); v1[3]=(short)f2bf(a0.w);
            v1[4]=(short)f2bf(a1.x); v1[5]=(short)f2bf(a1.y); v1[6]=(short)f2bf(a1.z); v1[7]=(short)f2bf(a1.w);
            v2[0]=(short)f2bf(c0.x); v2[1]=(short)f2bf(c0.y); v2[2]=(short)f2bf(c0.z); v2[3]=(short)f2bf(c0.w);
            v2[4]=(short)f2bf(c1.x); v2[5]=(short)f2bf(c1.y); v2[6]=(short)f2bf(c1.z); v2[7]=(short)f2bf(c1.w);
            bWg1[ct][kt] = v1;
            bWg2[ct][kt] = v2;
        }
        #pragma unroll
        for (int kt = 0; kt < 2; ++kt) {
            bf16x8 vv;
            #pragma unroll
            for (int e = 0; e < 8; ++e) {
                const int p = kt*32 + lg*8 + e;
                const float x = (p < NPOS_) ? Wpe[dout*NPOS_ + p] : 0.f;
                vv[e] = (short)f2bf(x);
            }
            bWpe[ct][kt] = vv;
        }
        bpe_c[ct] = bpe[dout];
        bg1_c[ct] = bg1[dout];
        bg2_c[ct] = bg2[dout];
        q_c[ct]   = qb[row*D_ + dout];
    }

    const float x4m0 = 4.f*xyz[row*3+0];
    const float x4m1 = 4.f*xyz[row*3+1];
    const float x4m2 = 4.f*xyz[row*3+2];

    // zero sParts (pads p>=33 must stay 0)
    for (int i = t; i < 32*64/2; i += 512) ((unsigned int*)sParts)[i] = 0u;
    __syncthreads();

    auto partsgen = [&](int n0) {
        const int n = t >> 4, j = t & 15;
        const int nr = (brow + n0 + n) * 3;
        const float pd0 = x4m0 - 4.f*xyz[nr+0];
        const float pd1 = x4m1 - 4.f*xyz[nr+1];
        const float pd2 = x4m2 - 4.f*xyz[nr+2];
        auto pval = [&](int p) -> float {
            if (p < 3) return p==0?pd0:(p==1?pd1:pd2);
            const int qq = p - 3;
            const int fi = qq / 6;
            int rem = qq - fi*6;
            bool is_sin = true;
            if (rem >= 3) { rem -= 3; is_sin = false; }
            const float pdj = rem==0?pd0:(rem==1?pd1:pd2);
            const float fr = fi==0?1.f:(fi==1?8.75f:(fi==2?16.5f:(fi==3?24.25f:32.f)));
            const float a = pdj * fr;
            return is_sin ? __sinf(a) : __cosf(a);
        };
        const int sw = (n & 7) << 3;
        sParts[(n*64 + j)      ^ sw] = f2bf(pval(j));
        sParts[(n*64 + j + 16) ^ sw] = f2bf(pval(j + 16));
        if (j == 0) sParts[(n*64 + 32) ^ sw] = f2bf(pval(32));
    };

    f32x4 pos[2];
    auto posedges = [&](int n0) {
        #pragma unroll
        for (int ct = 0; ct < 2; ++ct) {
            f32x4 acc = {0.f, 0.f, 0.f, 0.f};
            #pragma unroll
            for (int kt = 0; kt < 2; ++kt) {
                const int r16 = rb*16 + lr;
                const int idx = (r16*64 + kt*32 + lg*8) ^ ((r16 & 7) << 3);
                bf16x8 a = *(const bf16x8*)&sParts[idx];
                acc = MFMA(a, bWpe[ct][kt], acc);
            }
            #pragma unroll
            for (int r = 0; r < 4; ++r) acc[r] += bpe_c[ct];
            pos[ct] = acc;
        }
        #pragma unroll
        for (int ct = 0; ct < 2; ++ct) {
            const int d = (ct0 + ct)*16 + lr;
            #pragma unroll
            for (int r = 0; r < 4; ++r) {
                const int nl = rb*16 + lg*4 + r;
                const float e = pos[ct][r] + q_c[ct] - kb[(brow + n0 + nl)*D_ + d];
                sX[(nl*128 + d) ^ ((nl & 7) << 3)] = f2bf(e);
            }
        }
    };

    partsgen(0);
    __syncthreads();
    posedges(0);
    __syncthreads();

    float res_p[2] = {0.f, 0.f}, s_p[2] = {0.f, 0.f};

    for (int it = 0; it < N_/32; ++it) {
        const int n0 = it * 32;

        // ---- S1: h = relu(edges @ Wg1^T + bg1) -> sH ----
        f32x4 hacc[2];
        hacc[0] = (f32x4){bg1_c[0], bg1_c[0], bg1_c[0], bg1_c[0]};
        hacc[1] = (f32x4){bg1_c[1], bg1_c[1], bg1_c[1], bg1_c[1]};
        #pragma unroll
        for (int kt = 0; kt < 4; ++kt) {
            const int r16 = rb*16 + lr;
            const int idx = (r16*128 + kt*32 + lg*8) ^ ((r16 & 7) << 3);
            bf16x8 a = *(const bf16x8*)&sX[idx];
            hacc[0] = MFMA(a, bWg1[0][kt], hacc[0]);
            hacc[1] = MFMA(a, bWg1[1][kt], hacc[1]);
        }
        #pragma unroll
        for (int ct = 0; ct < 2; ++ct) {
            const int d = (ct0 + ct)*16 + lr;
            #pragma unroll
            for (int r = 0; r < 4; ++r) {
                const int nl = rb*16 + lg*4 + r;
                sH[(nl*128 + d) ^ ((nl & 7) << 3)] = f2bf(fmaxf(hacc[ct][r], 0.f));
            }
        }
        __syncthreads();

        // ---- S2: logits = h @ Wg2^T + bg2; exp/accumulate; gen parts(i+1) ----
        f32x4 lacc[2];
        lacc[0] = (f32x4){bg2_c[0], bg2_c[0], bg2_c[0], bg2_c[0]};
        lacc[1] = (f32x4){bg2_c[1], bg2_c[1], bg2_c[1], bg2_c[1]};
        #pragma unroll
        for (int kt = 0; kt < 4; ++kt) {
            const int r16 = rb*16 + lr;
            const int idx = (r16*128 + kt*32 + lg*8) ^ ((r16 & 7) << 3);
            bf16x8 a = *(const bf16x8*)&sH[idx];
            lacc[0] = MFMA(a, bWg2[0][kt], lacc[0]);
            lacc[1] = MFMA(a, bWg2[1][kt], lacc[1]);
        }
        #pragma unroll
        for (int ct = 0; ct < 2; ++ct) {
            const int d = (ct0 + ct)*16 + lr;
            #pragma unroll
            for (int r = 0; r < 4; ++r) {
                const int nl = rb*16 + lg*4 + r;
                const float wgt = __expf(lacc[ct][r]);
                const float vp = vb[(brow + n0 + nl)*D_ + d] + pos[ct][r];
                res_p[ct] += wgt * vp;
                s_p[ct]   += wgt;
            }
        }
        if (it < N_/32 - 1) partsgen(n0 + 32);
        __syncthreads();

        // ---- S3: pos GEMM + edges for iter i+1 -> sX ----
        if (it < N_/32 - 1) {
            posedges(n0 + 32);
            __syncthreads();
        }
    }

    // ---- cross-lane reduce then cross-rb reduce ----
    #pragma unroll
    for (int ct = 0; ct < 2; ++ct) {
        #pragma unroll
        for (int off = 16; off < 64; off <<= 1) {
            res_p[ct] += __shfl_xor(res_p[ct], off, 64);
            s_p[ct]   += __shfl_xor(s_p[ct], off, 64);
        }
    }
    if (lg < 2) {
        const int d = (ct0 + lg)*16 + lr;
        sRed[(rb*2+0)*128 + d] = (lg == 0) ? res_p[0] : res_p[1];
        sRed[(rb*2+1)*128 + d] = (lg == 0) ? s_p[0]   : s_p[1];
    }
    __syncthreads();
    if (t < D_) {
        const float rsum = sRed[t]       + sRed[2*128 + t];
        const float ssum = sRed[128 + t] + sRed[3*128 + t];
        float fres = graw[row*D_ + t];
        if (use_stats) fres = bn_apply(fres, stats_in, gam_in, bet_in, t);
        const float val = rsum / ssum + fres;
        gout[row*D_ + t] = val;
        atomicAdd(&stats_out[t], val);
        atomicAdd(&stats_out[128 + t], val*val);
    }
}

// ---------------- elementwise MLP (+ fused bn-apply in, bn-partials out) ----------------
__global__ __launch_bounds__(128) void em_kernel(const float* __restrict__ graw,
    const float* __restrict__ stats_in, const float* __restrict__ gam_in, const float* __restrict__ bet_in,
    const float* __restrict__ W1, const float* __restrict__ b1,
    const float* __restrict__ W2, const float* __restrict__ b2,
    float* __restrict__ gout, float* __restrict__ stats_out)
{
    __shared__ float row[D_], y1[D_];
    int r = blockIdx.x, d = threadIdx.x;
    float fn = bn_apply(graw[r*D_+d], stats_in, gam_in, bet_in, d);
    row[d] = fn; __syncthreads();
    float a = b1[d];
    #pragma unroll 4
    for (int e4=0;e4<D_/4;e4++){
        float4 w = *(const float4*)(W1 + d*D_ + e4*4);
        a += w.x*row[e4*4+0] + w.y*row[e4*4+1] + w.z*row[e4*4+2] + w.w*row[e4*4+3];
    }
    y1[d] = fmaxf(a,0.f); __syncthreads();
    float a2 = b2[d];
    #pragma unroll 4
    for (int e4=0;e4<D_/4;e4++){
        float4 w = *(const float4*)(W2 + d*D_ + e4*4);
        a2 += w.x*y1[e4*4+0] + w.y*y1[e4*4+1] + w.z*y1[e4*4+2] + w.w*y1[e4*4+3];
    }
    a2 = fmaxf(a2,0.f);
    const float g2 = fn + a2;
    gout[r*D_+d] = g2;
    atomicAdd(&stats_out[d], g2);
    atomicAdd(&stats_out[128+d], g2*g2);
}

// ---------------- final head (+ fused bn-apply) ----------------
__global__ __launch_bounds__(256) void final_kernel(const float* __restrict__ graw,
    const float* __restrict__ stats_in, const float* __restrict__ gam_in, const float* __restrict__ bet_in,
    const float* __restrict__ W1, const float* __restrict__ b1,
    const float* __restrict__ W2, const float* __restrict__ b2,
    float* __restrict__ e_ws)
{
    __shared__ float row[D_];
    __shared__ float h1[LAT_];
    int r = blockIdx.x, t = threadIdx.x;
    if (t < D_) row[t] = bn_apply(graw[r*D_+t], stats_in, gam_in, bet_in, t);
    __syncthreads();
    float a = b1[t];
    #pragma unroll 4
    for (int e4=0;e4<D_/4;e4++){
        float4 w = *(const float4*)(W1 + t*D_ + e4*4);
        a += w.x*row[e4*4+0] + w.y*row[e4*4+1] + w.z*row[e4*4+2] + w.w*row[e4*4+3];
    }
    h1[t] = fmaxf(a,0.f);
    __syncthreads();
    float a2 = b2[t];
    #pragma unroll 4
    for (int e4=0;e4<LAT_/4;e4++){
        float4 w = *(const float4*)(W2 + t*LAT_ + e4*4);
        a2 += w.x*h1[e4*4+0] + w.y*h1[e4*4+1] + w.z*h1[e4*4+2] + w.w*h1[e4*4+3];
    }
    e_ws[r*LAT_+t] = a2;
}

// ---------------- max over points ----------------
__global__ __launch_bounds__(256) void maxred_kernel(const float* __restrict__ e_ws,
                                                     float* __restrict__ out)
{
    int b = blockIdx.x, l = threadIdx.x;
    float m = -INFINITY;
    #pragma unroll 8
    for (int n=0;n<N_;n++) m = fmaxf(m, e_ws[(b*N_+n)*LAT_+l]);
    out[b*LAT_+l] = m;
}

extern "C" void kernel_launch(void* const* d_in, const int* in_sizes, int n_in,
                              void* d_out, int out_size, void* d_ws, size_t ws_size,
                              hipStream_t stream) {
    (void)in_sizes; (void)n_in; (void)out_size; (void)ws_size;
    const float* xyz    = (const float*)d_in[0];
    const float* feats  = (const float*)d_in[1];
    const float* enc_W  = (const float*)d_in[2];
    const float* enc_b  = (const float*)d_in[3];
    const float* tb_Wq  = (const float*)d_in[4];
    const float* tb_Wk  = (const float*)d_in[5];
    const float* tb_Wv  = (const float*)d_in[6];
    const float* tb_Wg1 = (const float*)d_in[7];
    const float* tb_bg1 = (const float*)d_in[8];
    const float* tb_Wg2 = (const float*)d_in[9];
    const float* tb_bg2 = (const float*)d_in[10];
    const float* tb_Wpe = (const float*)d_in[11];
    const float* tb_bpe = (const float*)d_in[12];
    const float* tb_gamma = (const float*)d_in[13];
    const float* tb_beta  = (const float*)d_in[14];
    const float* em_W1  = (const float*)d_in[15];
    const float* em_b1  = (const float*)d_in[16];
    const float* em_W2  = (const float*)d_in[17];
    const float* em_b2  = (const float*)d_in[18];
    const float* em_gamma = (const float*)d_in[19];
    const float* em_beta  = (const float*)d_in[20];
    const float* fcf_W1 = (const float*)d_in[21];
    const float* fcf_b1 = (const float*)d_in[22];
    const float* fcf_W2 = (const float*)d_in[23];
    const float* fcf_b2 = (const float*)d_in[24];
    float* out = (float*)d_out;

    // workspace layout (floats)
    float* ws   = (float*)d_ws;
    float* buf0 = ws;                      // ROWS_*D_
    float* buf1 = buf0 + ROWS_*D_;         // ROWS_*D_
    float* qbuf = buf1 + ROWS_*D_;
    float* kbuf = qbuf + ROWS_*D_;
    float* vbuf = kbuf + ROWS_*D_;
    float* ebuf = vbuf + ROWS_*D_;         // ROWS_*LAT_
    float* stats = ebuf + ROWS_*LAT_;      // 5 bn instances x 256 floats
    float* sA0 = stats;          // attn L0 out
    float* sA1 = stats + 256;    // attn L1 out
    float* sE1 = stats + 512;    // em  L1 out
    float* sA2 = stats + 768;    // attn L2 out
    float* sE2 = stats + 1024;   // em  L2 out

    hipMemsetAsync(stats, 0, 5*256*sizeof(float), stream);

    enc_kernel<<<(ROWS_*D_+255)/256, 256, 0, stream>>>(feats, enc_W, enc_b, buf0);

    const float* gz = tb_gamma;  // dummies for unused-stats calls
    // Layer 0
    qkv_kernel<<<ROWS_, 128, 0, stream>>>(buf0, gz, gz, gz, 0,
                                          tb_Wq, tb_Wk, tb_Wv, qbuf, kbuf, vbuf);
    attn_mfma_kernel<<<ROWS_, 512, 0, stream>>>(xyz, buf0, gz, gz, gz, 0,
        qbuf, kbuf, vbuf,
        tb_Wpe, tb_bpe, tb_Wg1, tb_bg1, tb_Wg2, tb_bg2, buf1, sA0);
    // Layer 1
    qkv_kernel<<<ROWS_, 128, 0, stream>>>(buf1, sA0, tb_gamma, tb_beta, 1,
                                          tb_Wq + 1*D_*D_, tb_Wk + 1*D_*D_, tb_Wv + 1*D_*D_,
                                          qbuf, kbuf, vbuf);
    attn_mfma_kernel<<<ROWS_, 512, 0, stream>>>(xyz, buf1, sA0, tb_gamma, tb_beta, 1,
        qbuf, kbuf, vbuf,
        tb_Wpe + 1*D_*NPOS_, tb_bpe + 1*D_, tb_Wg1 + 1*D_*D_, tb_bg1 + 1*D_,
        tb_Wg2 + 1*D_*D_, tb_bg2 + 1*D_, buf0, sA1);
    em_kernel<<<ROWS_, 128, 0, stream>>>(buf0, sA1, tb_gamma + 1*D_, tb_beta + 1*D_,
                                         em_W1, em_b1, em_W2, em_b2, buf1, sE1);
    // Layer 2
    qkv_kernel<<<ROWS_, 128, 0, stream>>>(buf1, sE1, em_gamma, em_beta, 1,
                                          tb_Wq + 2*D_*D_, tb_Wk + 2*D_*D_, tb_Wv + 2*D_*D_,
                                          qbuf, kbuf, vbuf);
    attn_mfma_kernel<<<ROWS_, 512, 0, stream>>>(xyz, buf1, sE1, em_gamma, em_beta, 1,
        qbuf, kbuf, vbuf,
        tb_Wpe + 2*D_*NPOS_, tb_bpe + 2*D_, tb_Wg1 + 2*D_*D_, tb_bg1 + 2*D_,
        tb_Wg2 + 2*D_*D_, tb_bg2 + 2*D_, buf0, sA2);
    em_kernel<<<ROWS_, 128, 0, stream>>>(buf0, sA2, tb_gamma + 2*D_, tb_beta + 2*D_,
                                         em_W1 + 1*D_*D_, em_b1 + 1*D_,
                                         em_W2 + 1*D_*D_, em_b2 + 1*D_, buf1, sE2);
    // Head
    final_kernel<<<ROWS_, 256, 0, stream>>>(buf1, sE2, em_gamma + 1*D_, em_beta + 1*D_,
                                            fcf_W1, fcf_b1, fcf_W2, fcf_b2, ebuf);
    maxred_kernel<<<B_, 256, 0, stream>>>(ebuf, out);
}

// Round 7
// 607.623 us; speedup vs baseline: 1.0873x; 1.0873x over previous
//
#include <hip/hip_runtime.h>
#include <hip/hip_bf16.h>

#define B_ 2
#define N_ 384
#define D_ 128
#define LAT_ 256
#define NPOS_ 33
#define ROWS_ (B_*N_)   // 768
#define NT_ 64          // n-rows per attn iteration
#define ITERS_ (N_/NT_) // 6

typedef __attribute__((ext_vector_type(8))) short bf16x8;
typedef __attribute__((ext_vector_type(4))) float f32x4;

#define MFMA(a,b,c) __builtin_amdgcn_mfma_f32_16x16x32_bf16((a),(b),(c),0,0,0)

__device__ __forceinline__ unsigned short f2bf(float x) {
    unsigned int u = __float_as_uint(x);
    u += 0x7FFFu + ((u >> 16) & 1u);   // round-to-nearest-even
    return (unsigned short)(u >> 16);
}

__device__ __forceinline__ float bn_apply(float x, const float* stats, const float* gam,
                                          const float* bet, int d) {
    float s  = stats[d], sq = stats[128 + d];
    float mean = s * (1.f/ROWS_);
    float var  = sq * (1.f/ROWS_) - mean*mean;
    return (x - mean) * rsqrtf(var + 1e-5f) * gam[d] + bet[d];
}

// ---------------- encode ----------------
__global__ __launch_bounds__(256) void enc_kernel(const float* __restrict__ feats,
                           const float* __restrict__ W,
                           const float* __restrict__ bias,
                           float* __restrict__ f) {
    int i = blockIdx.x*256 + threadIdx.x;
    if (i >= ROWS_*D_) return;
    int r = i >> 7, d = i & 127;
    f[i] = feats[r]*W[d] + bias[d];
}

// ---------------- qkv (+ fused bn-apply on input) ----------------
__global__ __launch_bounds__(128) void qkv_kernel(const float* __restrict__ graw,
    const float* __restrict__ stats, const float* __restrict__ gam, const float* __restrict__ bet,
    int use_stats,
    const float* __restrict__ Wq, const float* __restrict__ Wk, const float* __restrict__ Wv,
    float* __restrict__ q, float* __restrict__ k, float* __restrict__ v) {
    __shared__ float row[D_];
    int r = blockIdx.x, d = threadIdx.x;
    float x = graw[r*D_+d];
    if (use_stats) x = bn_apply(x, stats, gam, bet, d);
    row[d] = x;
    __syncthreads();
    float aq=0.f, ak=0.f, av=0.f;
    #pragma unroll 4
    for (int e4=0;e4<D_/4;e4++){
        float4 wq = *(const float4*)(Wq + d*D_ + e4*4);
        float4 wk = *(const float4*)(Wk + d*D_ + e4*4);
        float4 wv = *(const float4*)(Wv + d*D_ + e4*4);
        float x0=row[e4*4+0], x1=row[e4*4+1], x2=row[e4*4+2], x3=row[e4*4+3];
        aq += wq.x*x0 + wq.y*x1 + wq.z*x2 + wq.w*x3;
        ak += wk.x*x0 + wk.y*x1 + wk.z*x2 + wk.w*x3;
        av += wv.x*x0 + wv.y*x1 + wv.z*x2 + wv.w*x3;
    }
    q[r*D_+d]=aq; k[r*D_+d]=ak; v[r*D_+d]=av;
}

// ---------------- MFMA attention, NT=64 rows/iter, register K/V prefetch ----------------
// 512 thr = 8 waves: rb2 = w>>2 (n half: rows rb2*32..+32), ct0 = (w&3)*2 (two d-tiles).
// Per iter (3 barriers): S1 [loadV(it)] Wg1(sX->sH) | bar
//                        S2 [loadK(it+1)] Wg2(sH)->exp/accum(vreg); partsgen(it+1) | bar
//                        S3 posedges(it+1) via kreg -> sX | bar
// Register prefetch completes at the phase-end barrier drain (vmcnt(0) before s_barrier),
// hiding K/V L2 latency under the phase's MFMAs.
__global__ __launch_bounds__(512) void attn_mfma_kernel(
    const float* __restrict__ xyz, const float* __restrict__ graw,
    const float* __restrict__ stats_in, const float* __restrict__ gam_in,
    const float* __restrict__ bet_in, int use_stats,
    const float* __restrict__ qb, const float* __restrict__ kb, const float* __restrict__ vb,
    const float* __restrict__ Wpe, const float* __restrict__ bpe,
    const float* __restrict__ Wg1, const float* __restrict__ bg1,
    const float* __restrict__ Wg2, const float* __restrict__ bg2,
    float* __restrict__ gout, float* __restrict__ stats_out)
{
    __shared__ unsigned short sParts[NT_*64];   // bf16, swizzled, K-padded zeros (8KB)
    __shared__ unsigned short sX[NT_*128];      // edges bf16, swizzled (16KB)
    __shared__ unsigned short sH[NT_*128];      // h bf16, swizzled (16KB)
    __shared__ float sRed[4*128];

    const int t   = threadIdx.x;
    const int w   = t >> 6;
    const int l   = t & 63;
    const int lr  = l & 15;
    const int lg  = l >> 4;
    const int rb2 = w >> 2;           // which 32-row half of the 64-row tile
    const int ct0 = (w & 3) * 2;

    const int row  = blockIdx.x;
    const int b    = row / N_;
    const int brow = b * N_;

    // ---- prologue: register B-fragments (bf16) + per-col scalars ----
    bf16x8 bWg1[2][4], bWg2[2][4], bWpe[2][2];
    float  bpe_c[2], bg1_c[2], bg2_c[2], q_c[2];

    #pragma unroll
    for (int ct = 0; ct < 2; ++ct) {
        const int dout = (ct0 + ct) * 16 + lr;
        #pragma unroll
        for (int kt = 0; kt < 4; ++kt) {
            const float* p1 = Wg1 + dout * D_ + kt * 32 + lg * 8;
            const float* p2 = Wg2 + dout * D_ + kt * 32 + lg * 8;
            float4 a0 = *(const float4*)(p1);
            float4 a1 = *(const float4*)(p1 + 4);
            float4 c0 = *(const float4*)(p2);
            float4 c1 = *(const float4*)(p2 + 4);
            bf16x8 v1, v2;
            v1[0]=(short)f2bf(a0.x); v1[1]=(short)f2bf(a0.y); v1[2]=(short)f2bf(a0.z); v1[3]=(short)f2bf(a0.w);
            v1[4]=(short)f2bf(a1.x); v1[5]=(short)f2bf(a1.y); v1[6]=(short)f2bf(a1.z); v1[7]=(short)f2bf(a1.w);
            v2[0]=(short)f2bf(c0.x); v2[1]=(short)f2bf(c0.y); v2[2]=(short)f2bf(c0.z); v2[3]=(short)f2bf(c0.w);
            v2[4]=(short)f2bf(c1.x); v2[5]=(short)f2bf(c1.y); v2[6]=(short)f2bf(c1.z); v2[7]=(short)f2bf(c1.w);
            bWg1[ct][kt] = v1;
            bWg2[ct][kt] = v2;
        }
        #pragma unroll
        for (int kt = 0; kt < 2; ++kt) {
            bf16x8 vv;
            #pragma unroll
            for (int e = 0; e < 8; ++e) {
                const int p = kt*32 + lg*8 + e;
                const float x = (p < NPOS_) ? Wpe[dout*NPOS_ + p] : 0.f;
                vv[e] = (short)f2bf(x);
            }
            bWpe[ct][kt] = vv;
        }
        bpe_c[ct] = bpe[dout];
        bg1_c[ct] = bg1[dout];
        bg2_c[ct] = bg2[dout];
        q_c[ct]   = qb[row*D_ + dout];
    }

    const float x4m0 = 4.f*xyz[row*3+0];
    const float x4m1 = 4.f*xyz[row*3+1];
    const float x4m2 = 4.f*xyz[row*3+2];

    // zero sParts (pads p>=33 must stay 0)
    for (int i = t; i < NT_*64/2; i += 512) ((unsigned int*)sParts)[i] = 0u;
    __syncthreads();

    // 64 rows x 33 vals: thread handles row rr = t>>3, lanes j = t&7 do p = j+8k (+32 if j==0)
    auto partsgen = [&](int n0) {
        const int rr = t >> 3, j = t & 7;
        const int nr = (brow + n0 + rr) * 3;
        const float pd0 = x4m0 - 4.f*xyz[nr+0];
        const float pd1 = x4m1 - 4.f*xyz[nr+1];
        const float pd2 = x4m2 - 4.f*xyz[nr+2];
        auto pval = [&](int p) -> float {
            if (p < 3) return p==0?pd0:(p==1?pd1:pd2);
            const int qq = p - 3;
            const int fi = qq / 6;
            int rem = qq - fi*6;
            bool is_sin = true;
            if (rem >= 3) { rem -= 3; is_sin = false; }
            const float pdj = rem==0?pd0:(rem==1?pd1:pd2);
            const float fr = fi==0?1.f:(fi==1?8.75f:(fi==2?16.5f:(fi==3?24.25f:32.f)));
            const float a = pdj * fr;
            return is_sin ? __sinf(a) : __cosf(a);
        };
        const int sw = (rr & 7) << 3;
        #pragma unroll
        for (int k8 = 0; k8 < 4; ++k8) {
            const int p = j + k8*8;
            sParts[(rr*64 + p) ^ sw] = f2bf(pval(p));
        }
        if (j == 0) sParts[(rr*64 + 32) ^ sw] = f2bf(pval(32));
    };

    float kreg[2][2][4], vreg[2][2][4];
    auto loadK = [&](int n0) {
        #pragma unroll
        for (int rt = 0; rt < 2; ++rt)
        #pragma unroll
        for (int ct = 0; ct < 2; ++ct) {
            const int d = (ct0 + ct)*16 + lr;
            #pragma unroll
            for (int r = 0; r < 4; ++r) {
                const int rr = rb2*32 + rt*16 + lg*4 + r;
                kreg[rt][ct][r] = kb[(brow + n0 + rr)*D_ + d];
            }
        }
    };
    auto loadV = [&](int n0) {
        #pragma unroll
        for (int rt = 0; rt < 2; ++rt)
        #pragma unroll
        for (int ct = 0; ct < 2; ++ct) {
            const int d = (ct0 + ct)*16 + lr;
            #pragma unroll
            for (int r = 0; r < 4; ++r) {
                const int rr = rb2*32 + rt*16 + lg*4 + r;
                vreg[rt][ct][r] = vb[(brow + n0 + rr)*D_ + d];
            }
        }
    };

    f32x4 pos[2][2];
    auto posedges = [&]() {   // uses kreg already loaded
        #pragma unroll
        for (int rt = 0; rt < 2; ++rt)
        #pragma unroll
        for (int ct = 0; ct < 2; ++ct) {
            f32x4 acc = {0.f, 0.f, 0.f, 0.f};
            #pragma unroll
            for (int kt = 0; kt < 2; ++kt) {
                const int r16 = rb2*32 + rt*16 + lr;
                const int idx = (r16*64 + kt*32 + lg*8) ^ ((r16 & 7) << 3);
                bf16x8 a = *(const bf16x8*)&sParts[idx];
                acc = MFMA(a, bWpe[ct][kt], acc);
            }
            #pragma unroll
            for (int r = 0; r < 4; ++r) acc[r] += bpe_c[ct];
            pos[rt][ct] = acc;
        }
        #pragma unroll
        for (int rt = 0; rt < 2; ++rt)
        #pragma unroll
        for (int ct = 0; ct < 2; ++ct) {
            const int d = (ct0 + ct)*16 + lr;
            #pragma unroll
            for (int r = 0; r < 4; ++r) {
                const int rr = rb2*32 + rt*16 + lg*4 + r;
                const float e = pos[rt][ct][r] + q_c[ct] - kreg[rt][ct][r];
                sX[(rr*128 + d) ^ ((rr & 7) << 3)] = f2bf(e);
            }
        }
    };

    partsgen(0);
    __syncthreads();
    loadK(0);
    posedges();
    __syncthreads();

    float res_p[2] = {0.f, 0.f}, s_p[2] = {0.f, 0.f};

    for (int it = 0; it < ITERS_; ++it) {
        const int n0 = it * NT_;
        const bool more = (it < ITERS_ - 1);

        // ---- S1: prefetch V(it); h = relu(edges @ Wg1^T + bg1) -> sH ----
        loadV(n0);
        f32x4 hacc[2][2];
        #pragma unroll
        for (int rt = 0; rt < 2; ++rt) {
            hacc[rt][0] = (f32x4){bg1_c[0], bg1_c[0], bg1_c[0], bg1_c[0]};
            hacc[rt][1] = (f32x4){bg1_c[1], bg1_c[1], bg1_c[1], bg1_c[1]};
            #pragma unroll
            for (int kt = 0; kt < 4; ++kt) {
                const int r16 = rb2*32 + rt*16 + lr;
                const int idx = (r16*128 + kt*32 + lg*8) ^ ((r16 & 7) << 3);
                bf16x8 a = *(const bf16x8*)&sX[idx];
                hacc[rt][0] = MFMA(a, bWg1[0][kt], hacc[rt][0]);
                hacc[rt][1] = MFMA(a, bWg1[1][kt], hacc[rt][1]);
            }
        }
        #pragma unroll
        for (int rt = 0; rt < 2; ++rt)
        #pragma unroll
        for (int ct = 0; ct < 2; ++ct) {
            const int d = (ct0 + ct)*16 + lr;
            #pragma unroll
            for (int r = 0; r < 4; ++r) {
                const int rr = rb2*32 + rt*16 + lg*4 + r;
                sH[(rr*128 + d) ^ ((rr & 7) << 3)] = f2bf(fmaxf(hacc[rt][ct][r], 0.f));
            }
        }
        __syncthreads();

        // ---- S2: prefetch K(it+1); logits; exp/accumulate; partsgen(it+1) ----
        if (more) loadK(n0 + NT_);
        f32x4 lacc[2][2];
        #pragma unroll
        for (int rt = 0; rt < 2; ++rt) {
            lacc[rt][0] = (f32x4){bg2_c[0], bg2_c[0], bg2_c[0], bg2_c[0]};
            lacc[rt][1] = (f32x4){bg2_c[1], bg2_c[1], bg2_c[1], bg2_c[1]};
            #pragma unroll
            for (int kt = 0; kt < 4; ++kt) {
                const int r16 = rb2*32 + rt*16 + lr;
                const int idx = (r16*128 + kt*32 + lg*8) ^ ((r16 & 7) << 3);
                bf16x8 a = *(const bf16x8*)&sH[idx];
                lacc[rt][0] = MFMA(a, bWg2[0][kt], lacc[rt][0]);
                lacc[rt][1] = MFMA(a, bWg2[1][kt], lacc[rt][1]);
            }
        }
        #pragma unroll
        for (int rt = 0; rt < 2; ++rt)
        #pragma unroll
        for (int ct = 0; ct < 2; ++ct) {
            #pragma unroll
            for (int r = 0; r < 4; ++r) {
                const float wgt = __expf(lacc[rt][ct][r]);
                const float vp  = vreg[rt][ct][r] + pos[rt][ct][r];
                res_p[ct] += wgt * vp;
                s_p[ct]   += wgt;
            }
        }
        if (more) partsgen(n0 + NT_);
        __syncthreads();

        // ---- S3: pos GEMM + edges for it+1 -> sX ----
        if (more) {
            posedges();
            __syncthreads();
        }
    }

    // ---- cross-lane (n) reduce, then cross-rb2 reduce via LDS ----
    #pragma unroll
    for (int ct = 0; ct < 2; ++ct) {
        #pragma unroll
        for (int off = 16; off < 64; off <<= 1) {
            res_p[ct] += __shfl_xor(res_p[ct], off, 64);
            s_p[ct]   += __shfl_xor(s_p[ct], off, 64);
        }
    }
    if (lg == 0) {
        #pragma unroll
        for (int ct = 0; ct < 2; ++ct) {
            const int d = (ct0 + ct)*16 + lr;
            sRed[(rb2*2+0)*128 + d] = res_p[ct];
            sRed[(rb2*2+1)*128 + d] = s_p[ct];
        }
    }
    __syncthreads();
    if (t < D_) {
        const float rsum = sRed[t]       + sRed[2*128 + t];
        const float ssum = sRed[128 + t] + sRed[3*128 + t];
        float fres = graw[row*D_ + t];
        if (use_stats) fres = bn_apply(fres, stats_in, gam_in, bet_in, t);
        const float val = rsum / ssum + fres;
        gout[row*D_ + t] = val;
        atomicAdd(&stats_out[t], val);
        atomicAdd(&stats_out[128 + t], val*val);
    }
}

// ---------------- elementwise MLP (+ fused bn-apply in, bn-partials out) ----------------
__global__ __launch_bounds__(128) void em_kernel(const float* __restrict__ graw,
    const float* __restrict__ stats_in, const float* __restrict__ gam_in, const float* __restrict__ bet_in,
    const float* __restrict__ W1, const float* __restrict__ b1,
    const float* __restrict__ W2, const float* __restrict__ b2,
    float* __restrict__ gout, float* __restrict__ stats_out)
{
    __shared__ float row[D_], y1[D_];
    int r = blockIdx.x, d = threadIdx.x;
    float fn = bn_apply(graw[r*D_+d], stats_in, gam_in, bet_in, d);
    row[d] = fn; __syncthreads();
    float a = b1[d];
    #pragma unroll 4
    for (int e4=0;e4<D_/4;e4++){
        float4 w = *(const float4*)(W1 + d*D_ + e4*4);
        a += w.x*row[e4*4+0] + w.y*row[e4*4+1] + w.z*row[e4*4+2] + w.w*row[e4*4+3];
    }
    y1[d] = fmaxf(a,0.f); __syncthreads();
    float a2 = b2[d];
    #pragma unroll 4
    for (int e4=0;e4<D_/4;e4++){
        float4 w = *(const float4*)(W2 + d*D_ + e4*4);
        a2 += w.x*y1[e4*4+0] + w.y*y1[e4*4+1] + w.z*y1[e4*4+2] + w.w*y1[e4*4+3];
    }
    a2 = fmaxf(a2,0.f);
    const float g2 = fn + a2;
    gout[r*D_+d] = g2;
    atomicAdd(&stats_out[d], g2);
    atomicAdd(&stats_out[128+d], g2*g2);
}

// ---------------- final head (+ fused bn-apply) ----------------
__global__ __launch_bounds__(256) void final_kernel(const float* __restrict__ graw,
    const float* __restrict__ stats_in, const float* __restrict__ gam_in, const float* __restrict__ bet_in,
    const float* __restrict__ W1, const float* __restrict__ b1,
    const float* __restrict__ W2, const float* __restrict__ b2,
    float* __restrict__ e_ws)
{
    __shared__ float row[D_];
    __shared__ float h1[LAT_];
    int r = blockIdx.x, t = threadIdx.x;
    if (t < D_) row[t] = bn_apply(graw[r*D_+t], stats_in, gam_in, bet_in, t);
    __syncthreads();
    float a = b1[t];
    #pragma unroll 4
    for (int e4=0;e4<D_/4;e4++){
        float4 w = *(const float4*)(W1 + t*D_ + e4*4);
        a += w.x*row[e4*4+0] + w.y*row[e4*4+1] + w.z*row[e4*4+2] + w.w*row[e4*4+3];
    }
    h1[t] = fmaxf(a,0.f);
    __syncthreads();
    float a2 = b2[t];
    #pragma unroll 4
    for (int e4=0;e4<LAT_/4;e4++){
        float4 w = *(const float4*)(W2 + t*LAT_ + e4*4);
        a2 += w.x*h1[e4*4+0] + w.y*h1[e4*4+1] + w.z*h1[e4*4+2] + w.w*h1[e4*4+3];
    }
    e_ws[r*LAT_+t] = a2;
}

// ---------------- max over points ----------------
__global__ __launch_bounds__(256) void maxred_kernel(const float* __restrict__ e_ws,
                                                     float* __restrict__ out)
{
    int b = blockIdx.x, l = threadIdx.x;
    float m = -INFINITY;
    #pragma unroll 8
    for (int n=0;n<N_;n++) m = fmaxf(m, e_ws[(b*N_+n)*LAT_+l]);
    out[b*LAT_+l] = m;
}

extern "C" void kernel_launch(void* const* d_in, const int* in_sizes, int n_in,
                              void* d_out, int out_size, void* d_ws, size_t ws_size,
                              hipStream_t stream) {
    (void)in_sizes; (void)n_in; (void)out_size; (void)ws_size;
    const float* xyz    = (const float*)d_in[0];
    const float* feats  = (const float*)d_in[1];
    const float* enc_W  = (const float*)d_in[2];
    const float* enc_b  = (const float*)d_in[3];
    const float* tb_Wq  = (const float*)d_in[4];
    const float* tb_Wk  = (const float*)d_in[5];
    const float* tb_Wv  = (const float*)d_in[6];
    const float* tb_Wg1 = (const float*)d_in[7];
    const float* tb_bg1 = (const float*)d_in[8];
    const float* tb_Wg2 = (const float*)d_in[9];
    const float* tb_bg2 = (const float*)d_in[10];
    const float* tb_Wpe = (const float*)d_in[11];
    const float* tb_bpe = (const float*)d_in[12];
    const float* tb_gamma = (const float*)d_in[13];
    const float* tb_beta  = (const float*)d_in[14];
    const float* em_W1  = (const float*)d_in[15];
    const float* em_b1  = (const float*)d_in[16];
    const float* em_W2  = (const float*)d_in[17];
    const float* em_b2  = (const float*)d_in[18];
    const float* em_gamma = (const float*)d_in[19];
    const float* em_beta  = (const float*)d_in[20];
    const float* fcf_W1 = (const float*)d_in[21];
    const float* fcf_b1 = (const float*)d_in[22];
    const float* fcf_W2 = (const float*)d_in[23];
    const float* fcf_b2 = (const float*)d_in[24];
    float* out = (float*)d_out;

    // workspace layout (floats)
    float* ws   = (float*)d_ws;
    float* buf0 = ws;                      // ROWS_*D_
    float* buf1 = buf0 + ROWS_*D_;         // ROWS_*D_
    float* qbuf = buf1 + ROWS_*D_;
    float* kbuf = qbuf + ROWS_*D_;
    float* vbuf = kbuf + ROWS_*D_;
    float* ebuf = vbuf + ROWS_*D_;         // ROWS_*LAT_
    float* stats = ebuf + ROWS_*LAT_;      // 5 bn instances x 256 floats
    float* sA0 = stats;          // attn L0 out
    float* sA1 = stats + 256;    // attn L1 out
    float* sE1 = stats + 512;    // em  L1 out
    float* sA2 = stats + 768;    // attn L2 out
    float* sE2 = stats + 1024;   // em  L2 out

    hipMemsetAsync(stats, 0, 5*256*sizeof(float), stream);

    enc_kernel<<<(ROWS_*D_+255)/256, 256, 0, stream>>>(feats, enc_W, enc_b, buf0);

    const float* gz = tb_gamma;  // dummies for unused-stats calls
    // Layer 0
    qkv_kernel<<<ROWS_, 128, 0, stream>>>(buf0, gz, gz, gz, 0,
                                          tb_Wq, tb_Wk, tb_Wv, qbuf, kbuf, vbuf);
    attn_mfma_kernel<<<ROWS_, 512, 0, stream>>>(xyz, buf0, gz, gz, gz, 0,
        qbuf, kbuf, vbuf,
        tb_Wpe, tb_bpe, tb_Wg1, tb_bg1, tb_Wg2, tb_bg2, buf1, sA0);
    // Layer 1
    qkv_kernel<<<ROWS_, 128, 0, stream>>>(buf1, sA0, tb_gamma, tb_beta, 1,
                                          tb_Wq + 1*D_*D_, tb_Wk + 1*D_*D_, tb_Wv + 1*D_*D_,
                                          qbuf, kbuf, vbuf);
    attn_mfma_kernel<<<ROWS_, 512, 0, stream>>>(xyz, buf1, sA0, tb_gamma, tb_beta, 1,
        qbuf, kbuf, vbuf,
        tb_Wpe + 1*D_*NPOS_, tb_bpe + 1*D_, tb_Wg1 + 1*D_*D_, tb_bg1 + 1*D_,
        tb_Wg2 + 1*D_*D_, tb_bg2 + 1*D_, buf0, sA1);
    em_kernel<<<ROWS_, 128, 0, stream>>>(buf0, sA1, tb_gamma + 1*D_, tb_beta + 1*D_,
                                         em_W1, em_b1, em_W2, em_b2, buf1, sE1);
    // Layer 2
    qkv_kernel<<<ROWS_, 128, 0, stream>>>(buf1, sE1, em_gamma, em_beta, 1,
                                          tb_Wq + 2*D_*D_, tb_Wk + 2*D_*D_, tb_Wv + 2*D_*D_,
                                          qbuf, kbuf, vbuf);
    attn_mfma_kernel<<<ROWS_, 512, 0, stream>>>(xyz, buf1, sE1, em_gamma, em_beta, 1,
        qbuf, kbuf, vbuf,
        tb_Wpe + 2*D_*NPOS_, tb_bpe + 2*D_, tb_Wg1 + 2*D_*D_, tb_bg1 + 2*D_,
        tb_Wg2 + 2*D_*D_, tb_bg2 + 2*D_, buf0, sA2);
    em_kernel<<<ROWS_, 128, 0, stream>>>(buf0, sA2, tb_gamma + 2*D_, tb_beta + 2*D_,
                                         em_W1 + 1*D_*D_, em_b1 + 1*D_,
                                         em_W2 + 1*D_*D_, em_b2 + 1*D_, buf1, sE2);
    // Head
    final_kernel<<<ROWS_, 256, 0, stream>>>(buf1, sE2, em_gamma + 1*D_, em_beta + 1*D_,
                                            fcf_W1, fcf_b1, fcf_W2, fcf_b2, ebuf);
    maxred_kernel<<<B_, 256, 0, stream>>>(ebuf, out);
}